// Round 9
// baseline (61.724 us; speedup 1.0000x reference)
//
#include <hip/hip_runtime.h>
#include <math.h>

// Problem constants (fixed by harness)
#define NN   128
#define TT   1024
#define SS   1024
#define H1D  512
#define H2D  128
#define OUTD 8
#define KQN  8      // layer-1 split-K chunks

// NUFFT constants: grid Mr=2048 (2x oversampling), Gaussian width w=12
#define MR    2048
#define WHALF 5                    // k-5 in [-5,6]
#define ALPHA 0.3702402f           // pi/sqrt(72): balances trunc/alias err at e^-13.3
#define BETA  6.35556e-6f          // pi^2/(ALPHA*MR^2)
#define DSCALE 0.3432943f          // sqrt(ALPHA/pi)

// ws layout in floats (~2.9 MB)
#define OFF_FREQ 0                          // freq [n][s]
#define OFF_P1   (NN*SS)                    // 131072: P1 [8 kq][128 n][512 j]
#define OFF_H1   (OFF_P1 + KQN*NN*H1D)      // 655360  (end 720896)

__device__ __forceinline__ float cos_rev(float r) { return __builtin_amdgcn_cosf(r); } // cos(2*pi*r)
__device__ __forceinline__ float sin_rev(float r) { return __builtin_amdgcn_sinf(r); } // sin(2*pi*r)

// ---------------------------------------------------------------------------
// Kernel 1 (NEW): fused NUFFT per batch.  Block n, 512 threads.
//  a) twist c_t = x_t * e^{-2pi i 512 d_t}  (1 sincos/point)
//  b) fast Gaussian gridding onto 2048-bin periodic LDS grid, w=12
//     (3 exp/point; exp(-a(dl-k)^2) = E1 * rho^k * exp(-a k^2) table)
//  c) 2048-pt Stockham radix-2 FFT in LDS (11 stages, ping-pong, natural order)
//  d) deconvolve ghat(s') = sqrt(pi/a) e^{-b s'^2}, s = s'+512, magnitude
// Validation anchors: N=4 Stockham hand-check; DC test sum(w)*DSCALE = 1.00004.
// ---------------------------------------------------------------------------
__global__ __launch_bounds__(512) void k_spreadfft(const float* __restrict__ inp,
                                                   float* __restrict__ ws) {
    const int n   = blockIdx.x;
    const int tid = threadIdx.x;   // 0..511

    __shared__ float2 Ag[MR];
    __shared__ float2 Bg[MR];

    // zero grid
#pragma unroll
    for (int v = 0; v < MR / 512; ++v) Ag[v * 512 + tid] = make_float2(0.f, 0.f);

    // Gaussian table exp(-ALPHA*(k-5)^2), k=0..11 (register array, static idx)
    float T[12];
#pragma unroll
    for (int k = 0; k < 12; ++k) {
        const int kk = k - WHALF;
        T[k] = __expf(-ALPHA * (float)(kk * kk));
    }
    __syncthreads();

    // spread 2 points per thread
#pragma unroll
    for (int tt = 0; tt < 2; ++tt) {
        const int t = tid + tt * 512;
        const float* p = inp + (size_t)(n * TT + t) * 3;
        const float x  = p[0];
        const float d  = p[2];
        const float df = d - floorf(d);          // exact for |d| < 2^23
        // phase twist e^{-2pi i 512 d}: 512*df exact (pow2 scale)
        const float p512 = 512.0f * df;
        const float r512 = p512 - floorf(p512);
        const float cre = x * cos_rev(r512);
        const float cim = -x * sin_rev(r512);
        // grid position
        const float z  = df * 2048.0f;           // exact, [0,2048)
        const int   j0 = (int)z;
        const float dl = z - (float)j0;          // [0,1)
        // fast gridding factors
        float P = __expf(-ALPHA * dl * (dl + 10.0f));   // E1 * rho^-5
        const float R = __expf(2.0f * ALPHA * dl);      // rho
#pragma unroll
        for (int k = 0; k < 12; ++k) {
            const int gi = (j0 + k - WHALF) & (MR - 1);
            const float wk = P * T[k];
            atomicAdd(&Ag[gi].x, wk * cre);
            atomicAdd(&Ag[gi].y, wk * cim);
            P *= R;
        }
    }
    __syncthreads();

    // Stockham radix-2 FFT, N=2048: 11 stages, 1024 butterflies/stage,
    // 2 per thread. src[tau], src[tau+1024] -> dst[tau + (tau&~(m-1))] (+m).
    float2* src = Ag;
    float2* dst = Bg;
#pragma unroll
    for (int s = 0; s < 11; ++s) {
        const int   m     = 1 << s;
        const float inv2l = 1.0f / (float)(2048 >> s);
#pragma unroll
        for (int tt = 0; tt < 2; ++tt) {
            const int tau = tid + tt * 512;
            const int j   = tau >> s;
            const float r = (float)j * inv2l;            // exact: j / (2l)
            const float cv = cos_rev(r), sv = sin_rev(r); // w = cv - i*sv
            const float2 a = src[tau];
            const float2 b = src[tau + 1024];
            const int o = tau + (tau & ~(m - 1));
            dst[o] = make_float2(a.x + b.x, a.y + b.y);
            const float dr = a.x - b.x, di = a.y - b.y;
            dst[o + m] = make_float2(fmaf(di, sv, dr * cv),
                                     fmaf(di, cv, -dr * sv));
        }
        __syncthreads();
        float2* tmp = src; src = dst; dst = tmp;
    }

    // deconvolve + magnitude: s'=s-512, bin=(s+1536)&2047
    float* FREQ = ws + OFF_FREQ + (size_t)n * SS;
#pragma unroll
    for (int tt = 0; tt < 2; ++tt) {
        const int ss = tid + tt * 512;
        const int sp = ss - 512;
        const int bin = (ss + 1536) & (MR - 1);
        const float2 v = src[bin];
        const float D = DSCALE * __expf(BETA * (float)(sp * sp));
        FREQ[ss] = sqrtf(fmaf(v.x, v.x, v.y * v.y)) * D;
    }
}

// ---------------------------------------------------------------------------
// Kernel 2: layer-1 split-K partial GEMM (R8 verbatim, 8 k-chunks)
// ---------------------------------------------------------------------------
__global__ __launch_bounds__(256) void k_l1p(const float* __restrict__ W1,
                                             float* __restrict__ ws) {
    const int kq = blockIdx.x;   // 0..7   k-chunk of 128
    const int jq = blockIdx.y;   // 0..3   j-chunk of 128
    const int nb = blockIdx.z;   // 0..15  n-chunk of 8
    const int tid = threadIdx.x;

    __shared__ float4 Al[8][32];  // 8 n-rows x 128 k (as float4)
    const float4* FQ = (const float4*)(ws + OFF_FREQ);
    {
        const int row = tid >> 5, c4 = tid & 31;
        Al[row][c4] = FQ[(nb * 8 + row) * 256 + kq * 32 + c4];
    }
    __syncthreads();

    const int jl = tid & 127, ng = tid >> 7;
    const int j = jq * 128 + jl;
    const float4* W1v = (const float4*)W1;
    float a0 = 0.f, a1 = 0.f, a2 = 0.f, a3 = 0.f;
#pragma unroll 4
    for (int k4 = 0; k4 < 32; ++k4) {
        const float4 w  = W1v[(size_t)j * 256 + kq * 32 + k4];
        const float4 x0 = Al[ng * 4 + 0][k4];
        const float4 x1 = Al[ng * 4 + 1][k4];
        const float4 x2 = Al[ng * 4 + 2][k4];
        const float4 x3 = Al[ng * 4 + 3][k4];
        a0 = fmaf(x0.x, w.x, fmaf(x0.y, w.y, fmaf(x0.z, w.z, fmaf(x0.w, w.w, a0))));
        a1 = fmaf(x1.x, w.x, fmaf(x1.y, w.y, fmaf(x1.z, w.z, fmaf(x1.w, w.w, a1))));
        a2 = fmaf(x2.x, w.x, fmaf(x2.y, w.y, fmaf(x2.z, w.z, fmaf(x2.w, w.w, a2))));
        a3 = fmaf(x3.x, w.x, fmaf(x3.y, w.y, fmaf(x3.z, w.z, fmaf(x3.w, w.w, a3))));
    }
    float* P1 = ws + OFF_P1;
    const float acc[4] = {a0, a1, a2, a3};
#pragma unroll
    for (int i = 0; i < 4; ++i)
        P1[((size_t)(kq * NN + nb * 8 + ng * 4 + i)) * H1D + j] = acc[i];
}

// ---------------------------------------------------------------------------
// Kernel 3: combine layer-1 split-K partials + bias + sigmoid -> h1 (R8 verbatim)
// ---------------------------------------------------------------------------
__global__ __launch_bounds__(256) void k_l1c(const float* __restrict__ b1,
                                             float* __restrict__ ws) {
    const int tid = blockIdx.x * 256 + threadIdx.x;   // = n*H1D + j
    const int j = tid & (H1D - 1);
    float s = b1[j];
#pragma unroll
    for (int kq = 0; kq < KQN; ++kq) s += ws[OFF_P1 + (size_t)kq * (NN * H1D) + tid];
    ws[OFF_H1 + tid] = 1.0f / (1.0f + __expf(-s));
}

// ---------------------------------------------------------------------------
// Kernel 4: fused layers 2+3 (R8 verbatim)
// ---------------------------------------------------------------------------
__global__ __launch_bounds__(128) void k_l23(const float* __restrict__ W2,
                                             const float* __restrict__ b2,
                                             const float* __restrict__ W3,
                                             const float* __restrict__ b3,
                                             const float* __restrict__ ws,
                                             float* __restrict__ out) {
    const int n = blockIdx.x;
    const int j = threadIdx.x;   // 0..127

    __shared__ float4 h1l[128];  // h1 row (512 floats)
    __shared__ float  h2l[128];
    h1l[j] = ((const float4*)(ws + OFF_H1))[n * 128 + j];
    __syncthreads();

    const float4* W2v = (const float4*)W2;
    float a = b2[j];
#pragma unroll 4
    for (int k = 0; k < 128; ++k) {
        const float4 h = h1l[k];                    // broadcast
        const float4 w = W2v[(size_t)j * 128 + k];
        a = fmaf(h.x, w.x, fmaf(h.y, w.y, fmaf(h.z, w.z, fmaf(h.w, w.w, a))));
    }
    h2l[j] = 1.0f / (1.0f + __expf(-a));
    __syncthreads();

    if (j < OUTD) {
        float acc = b3[j];
        for (int q = 0; q < H2D; ++q) acc = fmaf(h2l[q], W3[j * H2D + q], acc);
        out[n * OUTD + j] = acc;
    }
}

extern "C" void kernel_launch(void* const* d_in, const int* in_sizes, int n_in,
                              void* d_out, int out_size, void* d_ws, size_t ws_size,
                              hipStream_t stream) {
    (void)in_sizes; (void)n_in; (void)out_size; (void)ws_size;
    const float* inp = (const float*)d_in[0];
    const float* W1  = (const float*)d_in[1];
    const float* b1  = (const float*)d_in[2];
    const float* W2  = (const float*)d_in[3];
    const float* b2  = (const float*)d_in[4];
    const float* W3  = (const float*)d_in[5];
    const float* b3  = (const float*)d_in[6];
    float* out = (float*)d_out;
    float* ws  = (float*)d_ws;

    k_spreadfft<<<dim3(NN),      dim3(512), 0, stream>>>(inp, ws);
    k_l1p      <<<dim3(8, 4, 16),dim3(256), 0, stream>>>(W1, ws);
    k_l1c      <<<dim3(256),     dim3(256), 0, stream>>>(b1, ws);
    k_l23      <<<dim3(128),     dim3(128), 0, stream>>>(W2, b2, W3, b3, ws, out);
}